// Round 4
// baseline (924.926 us; speedup 1.0000x reference)
//
#include <hip/hip_runtime.h>
#include <hip/hip_bf16.h>
#include <math.h>

// Problem constants
#define MTOK 16384   // B*N tokens
#define DDIM 1024
#define EEXP 8
#define FDIM 512
#define EFK  4096    // E*F flattened K for second GEMM

typedef __attribute__((ext_vector_type(8))) short short8;   // 8 bf16 = 4 VGPRs (MFMA A/B frag)
typedef __attribute__((ext_vector_type(4))) float floatx4;  // MFMA C/D frag

__device__ __forceinline__ void gld_lds16(const void* g, void* l) {
  // async global->LDS, 16B per lane, dest = wave-uniform base + lane*16
  __builtin_amdgcn_global_load_lds((const __attribute__((address_space(1))) void*)g,
                                   (__attribute__((address_space(3))) void*)l, 16, 0, 0);
}

// Fast exact-GELU via Abramowitz-Stegun 7.1.26 erf approx (|eps| <= 1.5e-7).
__device__ __forceinline__ float gelu_fast(float v) {
  const float z  = v * 0.70710678118654752f;
  const float az = fabsf(z);
  const float t  = __builtin_amdgcn_rcpf(1.f + 0.3275911f * az);
  const float poly = t * (0.254829592f +
                     t * (-0.284496736f +
                     t * (1.421413741f +
                     t * (-1.453152027f +
                     t * 1.061405429f))));
  const float ex = __expf(-az * az);
  float erfv = 1.f - poly * ex;
  erfv = copysignf(erfv, z);
  return 0.5f * v * (1.f + erfv);
}

// ---------------- transpose + fp32->bf16 cast: in [R,C] f32 -> out [C,R] bf16, batched in z
__global__ __launch_bounds__(256) void transpose_cast_kernel(
    const float* __restrict__ in, __hip_bfloat16* __restrict__ out, int R, int C) {
  __shared__ float tile[32][33];
  const float* inb = in + (size_t)blockIdx.z * R * C;
  __hip_bfloat16* outb = out + (size_t)blockIdx.z * R * C;
  const int c0 = blockIdx.x * 32, r0 = blockIdx.y * 32;
  const int tx = threadIdx.x & 31, ty = threadIdx.x >> 5;  // 32 x 8
#pragma unroll
  for (int i = 0; i < 4; ++i)
    tile[ty + i * 8][tx] = inb[(size_t)(r0 + ty + i * 8) * C + (c0 + tx)];
  __syncthreads();
#pragma unroll
  for (int i = 0; i < 4; ++i)
    outb[(size_t)(c0 + ty + i * 8) * R + (r0 + tx)] = __float2bfloat16(tile[tx][ty + i * 8]);
}

// ---------------- router softmax (fp32) + x -> bf16 cast. One wave per token.
__global__ __launch_bounds__(256) void router_cast_kernel(
    const float* __restrict__ x, const float* __restrict__ Wr, const float* __restrict__ br,
    __hip_bfloat16* __restrict__ xbf, float* __restrict__ r) {
  const int wave = (blockIdx.x * 256 + threadIdx.x) >> 6;  // token id
  const int lane = threadIdx.x & 63;
  const float* xr = x + (size_t)wave * DDIM;
  float acc[EEXP];
#pragma unroll
  for (int e = 0; e < EEXP; ++e) acc[e] = 0.f;
#pragma unroll
  for (int i = 0; i < DDIM / 64; ++i) {
    const int d = i * 64 + lane;
    const float xv = xr[d];
    xbf[(size_t)wave * DDIM + d] = __float2bfloat16(xv);
    const float4* w4 = (const float4*)(Wr + (size_t)d * EEXP);
    const float4 w0 = w4[0], w1 = w4[1];
    acc[0] += xv * w0.x; acc[1] += xv * w0.y; acc[2] += xv * w0.z; acc[3] += xv * w0.w;
    acc[4] += xv * w1.x; acc[5] += xv * w1.y; acc[6] += xv * w1.z; acc[7] += xv * w1.w;
  }
#pragma unroll
  for (int off = 32; off; off >>= 1) {
#pragma unroll
    for (int e = 0; e < EEXP; ++e) acc[e] += __shfl_xor(acc[e], off, 64);
  }
  float mx = -1e30f;
#pragma unroll
  for (int e = 0; e < EEXP; ++e) { acc[e] += br[e]; mx = fmaxf(mx, acc[e]); }
  float s = 0.f;
#pragma unroll
  for (int e = 0; e < EEXP; ++e) { acc[e] = expf(acc[e] - mx); s += acc[e]; }
  const float inv = 1.f / s;
  if (lane < EEXP) r[(size_t)wave * EEXP + lane] = acc[lane] * inv;
}

// ============ shared GEMM geometry: 512 threads (8 waves), tile M=128 tok x N=256,
// BK=32, dbuf LDS 48 KiB (A 128x32 + B 256x32 per buffer), 3 blocks/CU.
// Wave grid: ng = wid>>1 (4 x 64 N-rows), tg = wid&1 (2 x 64 tok).
// Staging: 3 full-block rounds/iter: A rows 0..127, B rows 0..127, B rows 128..255.
// MFMA operand swap: A-operand = weight rows (m = f/d), B-operand = token rows (n = tok)
// -> C/D lane mapping: m-row = laneq*4 + reg (4 consecutive), n-col = lanem.

#define TILE_A_ELEMS (128 * 32)           // 4096 elems, 8 KiB
#define TILE_ELEMS   ((128 + 256) * 32)   // per-buffer total: 12288 elems, 24 KiB

// ---------------- GEMM 1: Hs[tok][e*F+f] = bf16( gelu(x @ W1[e] + b1[e]) * r[tok,e] )
__global__ __launch_bounds__(512, 6) void gemm_h_kernel(
    const __hip_bfloat16* __restrict__ A, const __hip_bfloat16* __restrict__ W1t,
    const float* __restrict__ b1, const float* __restrict__ r,
    __hip_bfloat16* __restrict__ Hs) {
  const int M0 = blockIdx.x * 128;           // token strip
  const int F0 = blockIdx.y * 256;           // f half
  const int e  = blockIdx.z;

  __shared__ __hip_bfloat16 lds[2][TILE_ELEMS];

  const int tid  = threadIdx.x;
  const int lane = tid & 63;
  const int wid  = tid >> 6;
  const int fg = (wid >> 1) * 64;            // wave f offset in tile
  const int tg = (wid & 1) * 64;             // wave tok offset in tile
  const int laneq = lane >> 4;
  const int lanem = lane & 15;
  const int srow = tid >> 2;                 // 0..127 staging row
  const int cc8  = (tid & 3) * 8;            // 16B chunk within 32-elem row

  const __hip_bfloat16* gA = A + (size_t)(M0 + srow) * DDIM + cc8;
  const __hip_bfloat16* gB = W1t + (size_t)e * FDIM * DDIM + (size_t)(F0 + srow) * DDIM + cc8;
  const __hip_bfloat16* gB2 = gB + (size_t)128 * DDIM;

  floatx4 acc[4][4];   // [i = f group][j = tok group]
#pragma unroll
  for (int i = 0; i < 4; ++i)
#pragma unroll
    for (int j = 0; j < 4; ++j) acc[i][j] = (floatx4){0.f, 0.f, 0.f, 0.f};

#define STAGEH(p, k0)                                               \
  do {                                                              \
    gld_lds16(gA  + (k0), &lds[p][(size_t)tid * 8]);                \
    gld_lds16(gB  + (k0), &lds[p][(size_t)(512 + tid) * 8]);        \
    gld_lds16(gB2 + (k0), &lds[p][(size_t)(1024 + tid) * 8]);       \
  } while (0)

  STAGEH(0, 0);
  const int KT = DDIM / 32;
  for (int kt = 0; kt < KT; ++kt) {
    const int p = kt & 1;
    __syncthreads();                          // tile kt ready; prev reads of buf p^1 retired
    if (kt + 1 < KT) STAGEH(p ^ 1, (kt + 1) * 32);
    short8 wfr[4], xfr[4];
#pragma unroll
    for (int i = 0; i < 4; ++i)
      wfr[i] = *(const short8*)(&lds[p][TILE_A_ELEMS + (fg + i * 16 + lanem) * 32 + laneq * 8]);
#pragma unroll
    for (int j = 0; j < 4; ++j)
      xfr[j] = *(const short8*)(&lds[p][(tg + j * 16 + lanem) * 32 + laneq * 8]);
#pragma unroll
    for (int i = 0; i < 4; ++i)
#pragma unroll
      for (int j = 0; j < 4; ++j)
        acc[i][j] = __builtin_amdgcn_mfma_f32_16x16x32_bf16(wfr[i], xfr[j], acc[i][j], 0, 0, 0);
  }
#undef STAGEH

  // epilogue: bias -> fast exact-gelu -> router scale -> packed bf16x4 store
#pragma unroll
  for (int j = 0; j < 4; ++j) {
    const int tok = M0 + tg + j * 16 + lanem;
    const float rv = r[(size_t)tok * EEXP + e];
#pragma unroll
    for (int i = 0; i < 4; ++i) {
      const int f = F0 + fg + i * 16 + laneq * 4;        // 4 consecutive f
      const float4 b4 = *(const float4*)(b1 + e * FDIM + f);
      union { ushort4 u; __hip_bfloat16 h[4]; } pk;
      pk.h[0] = __float2bfloat16(gelu_fast(acc[i][j][0] + b4.x) * rv);
      pk.h[1] = __float2bfloat16(gelu_fast(acc[i][j][1] + b4.y) * rv);
      pk.h[2] = __float2bfloat16(gelu_fast(acc[i][j][2] + b4.z) * rv);
      pk.h[3] = __float2bfloat16(gelu_fast(acc[i][j][3] + b4.w) * rv);
      *(ushort4*)(Hs + (size_t)tok * EFK + e * FDIM + f) = pk.u;
    }
  }
}

// ---------------- GEMM 2: out[tok][d] = Hs[tok,:] @ W2flat[:,d] + sum_e r[tok,e]*b2[e,d]
// Flat grid of 512 blocks; bx swizzled so the 4 d-quarter blocks of one token
// strip are dispatch-adjacent -> concurrent -> Hs strip L3-hot after first fetch.
__global__ __launch_bounds__(512, 4) void gemm_out_kernel(
    const __hip_bfloat16* __restrict__ Hs, const __hip_bfloat16* __restrict__ W2t,
    const float* __restrict__ b2, const float* __restrict__ r,
    float* __restrict__ out) {
  const int M0 = (blockIdx.x >> 2) * 128;    // token strip
  const int N0 = (blockIdx.x & 3) * 256;     // d quarter

  __shared__ __hip_bfloat16 lds[2][TILE_ELEMS];

  const int tid  = threadIdx.x;
  const int lane = tid & 63;
  const int wid  = tid >> 6;
  const int dg = (wid >> 1) * 64;            // wave d offset in tile
  const int tg = (wid & 1) * 64;             // wave tok offset in tile
  const int laneq = lane >> 4;
  const int lanem = lane & 15;
  const int srow = tid >> 2;
  const int cc8  = (tid & 3) * 8;

  const __hip_bfloat16* gA = Hs + (size_t)(M0 + srow) * EFK + cc8;
  const __hip_bfloat16* gB = W2t + (size_t)(N0 + srow) * EFK + cc8;
  const __hip_bfloat16* gB2 = gB + (size_t)128 * EFK;

  floatx4 acc[4][4];   // [i = d group][j = tok group]
#pragma unroll
  for (int i = 0; i < 4; ++i)
#pragma unroll
    for (int j = 0; j < 4; ++j) acc[i][j] = (floatx4){0.f, 0.f, 0.f, 0.f};

#define STAGEO(p, k0)                                               \
  do {                                                              \
    gld_lds16(gA  + (k0), &lds[p][(size_t)tid * 8]);                \
    gld_lds16(gB  + (k0), &lds[p][(size_t)(512 + tid) * 8]);        \
    gld_lds16(gB2 + (k0), &lds[p][(size_t)(1024 + tid) * 8]);       \
  } while (0)

  STAGEO(0, 0);
  const int KT = EFK / 32;
  for (int kt = 0; kt < KT; ++kt) {
    const int p = kt & 1;
    __syncthreads();
    if (kt + 1 < KT) STAGEO(p ^ 1, (kt + 1) * 32);
    short8 wfr[4], hfr[4];
#pragma unroll
    for (int i = 0; i < 4; ++i)
      wfr[i] = *(const short8*)(&lds[p][TILE_A_ELEMS + (dg + i * 16 + lanem) * 32 + laneq * 8]);
#pragma unroll
    for (int j = 0; j < 4; ++j)
      hfr[j] = *(const short8*)(&lds[p][(tg + j * 16 + lanem) * 32 + laneq * 8]);
#pragma unroll
    for (int i = 0; i < 4; ++i)
#pragma unroll
      for (int j = 0; j < 4; ++j)
        acc[i][j] = __builtin_amdgcn_mfma_f32_16x16x32_bf16(wfr[i], hfr[j], acc[i][j], 0, 0, 0);
  }
#undef STAGEO

  // epilogue: combined bias sum_e r[tok,e]*b2[e,d], float4 store
#pragma unroll
  for (int i = 0; i < 4; ++i) {
    const int d0 = N0 + dg + i * 16 + laneq * 4;         // 4 consecutive d
    float4 b2v[EEXP];
#pragma unroll
    for (int e = 0; e < EEXP; ++e) b2v[e] = *(const float4*)(b2 + e * DDIM + d0);
#pragma unroll
    for (int j = 0; j < 4; ++j) {
      const int tok = M0 + tg + j * 16 + lanem;
      const float4* r4 = (const float4*)(r + (size_t)tok * EEXP);
      const float4 r0 = r4[0], r1 = r4[1];
      const float rv[EEXP] = {r0.x, r0.y, r0.z, r0.w, r1.x, r1.y, r1.z, r1.w};
      float bx = 0.f, by = 0.f, bz = 0.f, bw = 0.f;
#pragma unroll
      for (int e = 0; e < EEXP; ++e) {
        bx += rv[e] * b2v[e].x; by += rv[e] * b2v[e].y;
        bz += rv[e] * b2v[e].z; bw += rv[e] * b2v[e].w;
      }
      float4 o;
      o.x = acc[i][j][0] + bx; o.y = acc[i][j][1] + by;
      o.z = acc[i][j][2] + bz; o.w = acc[i][j][3] + bw;
      *(float4*)(out + (size_t)tok * DDIM + d0) = o;
    }
  }
}

extern "C" void kernel_launch(void* const* d_in, const int* in_sizes, int n_in,
                              void* d_out, int out_size, void* d_ws, size_t ws_size,
                              hipStream_t stream) {
  const float* x  = (const float*)d_in[0];
  const float* W1 = (const float*)d_in[1];
  const float* b1 = (const float*)d_in[2];
  const float* W2 = (const float*)d_in[3];
  const float* b2 = (const float*)d_in[4];
  const float* Wr = (const float*)d_in[5];
  const float* br = (const float*)d_in[6];
  float* out = (float*)d_out;

  char* ws = (char*)d_ws;
  __hip_bfloat16* xbf = (__hip_bfloat16*)(ws);                            // 32 MB
  __hip_bfloat16* W1t = (__hip_bfloat16*)(ws + (32u << 20));              // 8 MB  [E][F][D]
  __hip_bfloat16* W2t = (__hip_bfloat16*)(ws + (40u << 20));              // 8 MB  [D][E*F]
  float*          r   = (float*)(ws + (48u << 20));                       // 0.5 MB [MTOK][E]
  __hip_bfloat16* Hs  = (__hip_bfloat16*)(ws + (48u << 20) + (1u << 19)); // 128 MB [MTOK][E*F]

  // W1 [E][D][F] -> W1t [E][F][D]
  transpose_cast_kernel<<<dim3(FDIM / 32, DDIM / 32, EEXP), 256, 0, stream>>>(W1, W1t, DDIM, FDIM);
  // W2 [E*F][D] -> W2t [D][E*F]
  transpose_cast_kernel<<<dim3(DDIM / 32, EFK / 32, 1), 256, 0, stream>>>(W2, W2t, EFK, DDIM);
  // router softmax + x cast
  router_cast_kernel<<<MTOK / 4, 256, 0, stream>>>(x, Wr, br, xbf, r);
  // stage 1 grouped GEMM (+gelu, +router scale): 128-tok x 256-f tiles
  gemm_h_kernel<<<dim3(MTOK / 128, FDIM / 256, EEXP), 512, 0, stream>>>(xbf, W1t, b1, r, Hs);
  // stage 2 GEMM (+combined bias): 128-tok x 256-d tiles, swizzled flat grid
  gemm_out_kernel<<<dim3((MTOK / 128) * (DDIM / 256)), 512, 0, stream>>>(Hs, W2t, b2, r, out);
}

// Round 5
// 525.905 us; speedup vs baseline: 1.7587x; 1.7587x over previous
//
#include <hip/hip_runtime.h>
#include <hip/hip_bf16.h>
#include <math.h>

// Problem constants
#define MTOK 16384   // B*N tokens
#define DDIM 1024
#define EEXP 8
#define FDIM 512
#define EFK  4096    // E*F flattened K for second GEMM

typedef __attribute__((ext_vector_type(8))) short short8;   // 8 bf16 = 4 VGPRs (MFMA A/B frag)
typedef __attribute__((ext_vector_type(4))) float floatx4;  // MFMA C/D frag

__device__ __forceinline__ void gld_lds16(const void* g, void* l) {
  // async global->LDS, 16B per lane, dest = wave-uniform base + lane*16
  __builtin_amdgcn_global_load_lds((const __attribute__((address_space(1))) void*)g,
                                   (__attribute__((address_space(3))) void*)l, 16, 0, 0);
}

// Fast exact-GELU via Abramowitz-Stegun 7.1.26 erf approx (|eps| <= 1.5e-7).
__device__ __forceinline__ float gelu_fast(float v) {
  const float z  = v * 0.70710678118654752f;
  const float az = fabsf(z);
  const float t  = __builtin_amdgcn_rcpf(1.f + 0.3275911f * az);
  const float poly = t * (0.254829592f +
                     t * (-0.284496736f +
                     t * (1.421413741f +
                     t * (-1.453152027f +
                     t * 1.061405429f))));
  const float ex = __expf(-az * az);
  float erfv = 1.f - poly * ex;
  erfv = copysignf(erfv, z);
  return 0.5f * v * (1.f + erfv);
}

// ---------------- transpose + fp32->bf16 cast: in [R,C] f32 -> out [C,R] bf16, batched in z
__global__ __launch_bounds__(256) void transpose_cast_kernel(
    const float* __restrict__ in, __hip_bfloat16* __restrict__ out, int R, int C) {
  __shared__ float tile[32][33];
  const float* inb = in + (size_t)blockIdx.z * R * C;
  __hip_bfloat16* outb = out + (size_t)blockIdx.z * R * C;
  const int c0 = blockIdx.x * 32, r0 = blockIdx.y * 32;
  const int tx = threadIdx.x & 31, ty = threadIdx.x >> 5;  // 32 x 8
#pragma unroll
  for (int i = 0; i < 4; ++i)
    tile[ty + i * 8][tx] = inb[(size_t)(r0 + ty + i * 8) * C + (c0 + tx)];
  __syncthreads();
#pragma unroll
  for (int i = 0; i < 4; ++i)
    outb[(size_t)(c0 + ty + i * 8) * R + (r0 + tx)] = __float2bfloat16(tile[tx][ty + i * 8]);
}

// ---------------- router softmax (fp32) + x -> bf16 cast. One wave per token.
__global__ __launch_bounds__(256) void router_cast_kernel(
    const float* __restrict__ x, const float* __restrict__ Wr, const float* __restrict__ br,
    __hip_bfloat16* __restrict__ xbf, float* __restrict__ r) {
  const int wave = (blockIdx.x * 256 + threadIdx.x) >> 6;  // token id
  const int lane = threadIdx.x & 63;
  const float* xr = x + (size_t)wave * DDIM;
  float acc[EEXP];
#pragma unroll
  for (int e = 0; e < EEXP; ++e) acc[e] = 0.f;
#pragma unroll
  for (int i = 0; i < DDIM / 64; ++i) {
    const int d = i * 64 + lane;
    const float xv = xr[d];
    xbf[(size_t)wave * DDIM + d] = __float2bfloat16(xv);
    const float4* w4 = (const float4*)(Wr + (size_t)d * EEXP);
    const float4 w0 = w4[0], w1 = w4[1];
    acc[0] += xv * w0.x; acc[1] += xv * w0.y; acc[2] += xv * w0.z; acc[3] += xv * w0.w;
    acc[4] += xv * w1.x; acc[5] += xv * w1.y; acc[6] += xv * w1.z; acc[7] += xv * w1.w;
  }
#pragma unroll
  for (int off = 32; off; off >>= 1) {
#pragma unroll
    for (int e = 0; e < EEXP; ++e) acc[e] += __shfl_xor(acc[e], off, 64);
  }
  float mx = -1e30f;
#pragma unroll
  for (int e = 0; e < EEXP; ++e) { acc[e] += br[e]; mx = fmaxf(mx, acc[e]); }
  float s = 0.f;
#pragma unroll
  for (int e = 0; e < EEXP; ++e) { acc[e] = expf(acc[e] - mx); s += acc[e]; }
  const float inv = 1.f / s;
  if (lane < EEXP) r[(size_t)wave * EEXP + lane] = acc[lane] * inv;
}

// ============ shared GEMM geometry: 512 threads (8 waves), tile M=128 tok x N=256,
// BK=32, dbuf LDS 48 KiB (A 128x32 + B 256x32 per buffer).
// __launch_bounds__(512, 4): 4 waves/EU -> 128 regs/wave budget = 64 AGPR acc +
// 64 VGPR, NO SPILL (R4's (512,6) forced an 85-reg budget -> accumulator spill
// -> 1.6 GB scratch traffic). 2 blocks/CU, 16 waves/CU.
// Staging: 3 full-block rounds/iter: A rows 0..127, B rows 0..127, B rows 128..255.
// MFMA operand swap: A-operand = weight rows (m = f/d), B-operand = token rows (n = tok)
// -> C/D lane mapping: m-row = laneq*4 + reg (4 consecutive), n-col = lanem.

#define TILE_A_ELEMS (128 * 32)           // 4096 elems, 8 KiB
#define TILE_ELEMS   ((128 + 256) * 32)   // per-buffer total: 12288 elems, 24 KiB

// ---------------- GEMM 1: Hs[tok][e*F+f] = bf16( gelu(x @ W1[e] + b1[e]) * r[tok,e] )
__global__ __launch_bounds__(512, 4) void gemm_h_kernel(
    const __hip_bfloat16* __restrict__ A, const __hip_bfloat16* __restrict__ W1t,
    const float* __restrict__ b1, const float* __restrict__ r,
    __hip_bfloat16* __restrict__ Hs) {
  const int M0 = blockIdx.x * 128;           // token strip
  const int F0 = blockIdx.y * 256;           // f half
  const int e  = blockIdx.z;

  __shared__ __hip_bfloat16 lds[2][TILE_ELEMS];

  const int tid  = threadIdx.x;
  const int lane = tid & 63;
  const int wid  = tid >> 6;
  const int fg = (wid >> 1) * 64;            // wave f offset in tile
  const int tg = (wid & 1) * 64;             // wave tok offset in tile
  const int laneq = lane >> 4;
  const int lanem = lane & 15;
  const int srow = tid >> 2;                 // 0..127 staging row
  const int cc8  = (tid & 3) * 8;            // 16B chunk within 32-elem row

  const __hip_bfloat16* gA = A + (size_t)(M0 + srow) * DDIM + cc8;
  const __hip_bfloat16* gB = W1t + (size_t)e * FDIM * DDIM + (size_t)(F0 + srow) * DDIM + cc8;
  const __hip_bfloat16* gB2 = gB + (size_t)128 * DDIM;

  floatx4 acc[4][4];   // [i = f group][j = tok group]
#pragma unroll
  for (int i = 0; i < 4; ++i)
#pragma unroll
    for (int j = 0; j < 4; ++j) acc[i][j] = (floatx4){0.f, 0.f, 0.f, 0.f};

#define STAGEH(p, k0)                                               \
  do {                                                              \
    gld_lds16(gA  + (k0), &lds[p][(size_t)tid * 8]);                \
    gld_lds16(gB  + (k0), &lds[p][(size_t)(512 + tid) * 8]);        \
    gld_lds16(gB2 + (k0), &lds[p][(size_t)(1024 + tid) * 8]);       \
  } while (0)

  STAGEH(0, 0);
  const int KT = DDIM / 32;
  for (int kt = 0; kt < KT; ++kt) {
    const int p = kt & 1;
    __syncthreads();                          // tile kt ready; prev reads of buf p^1 retired
    if (kt + 1 < KT) STAGEH(p ^ 1, (kt + 1) * 32);
    short8 wfr[4], xfr[4];
#pragma unroll
    for (int i = 0; i < 4; ++i)
      wfr[i] = *(const short8*)(&lds[p][TILE_A_ELEMS + (fg + i * 16 + lanem) * 32 + laneq * 8]);
#pragma unroll
    for (int j = 0; j < 4; ++j)
      xfr[j] = *(const short8*)(&lds[p][(tg + j * 16 + lanem) * 32 + laneq * 8]);
#pragma unroll
    for (int i = 0; i < 4; ++i)
#pragma unroll
      for (int j = 0; j < 4; ++j)
        acc[i][j] = __builtin_amdgcn_mfma_f32_16x16x32_bf16(wfr[i], xfr[j], acc[i][j], 0, 0, 0);
  }
#undef STAGEH

  // epilogue: bias -> fast exact-gelu -> router scale -> packed bf16x4 store
#pragma unroll
  for (int j = 0; j < 4; ++j) {
    const int tok = M0 + tg + j * 16 + lanem;
    const float rv = r[(size_t)tok * EEXP + e];
#pragma unroll
    for (int i = 0; i < 4; ++i) {
      const int f = F0 + fg + i * 16 + laneq * 4;        // 4 consecutive f
      const float4 b4 = *(const float4*)(b1 + e * FDIM + f);
      union { ushort4 u; __hip_bfloat16 h[4]; } pk;
      pk.h[0] = __float2bfloat16(gelu_fast(acc[i][j][0] + b4.x) * rv);
      pk.h[1] = __float2bfloat16(gelu_fast(acc[i][j][1] + b4.y) * rv);
      pk.h[2] = __float2bfloat16(gelu_fast(acc[i][j][2] + b4.z) * rv);
      pk.h[3] = __float2bfloat16(gelu_fast(acc[i][j][3] + b4.w) * rv);
      *(ushort4*)(Hs + (size_t)tok * EFK + e * FDIM + f) = pk.u;
    }
  }
}

// ---------------- GEMM 2: out[tok][d] = Hs[tok,:] @ W2flat[:,d] + sum_e r[tok,e]*b2[e,d]
// Flat grid of 512 blocks; bx swizzled so the 4 d-quarter blocks of one token
// strip are dispatch-adjacent -> concurrent -> Hs strip L3-hot after first fetch.
__global__ __launch_bounds__(512, 4) void gemm_out_kernel(
    const __hip_bfloat16* __restrict__ Hs, const __hip_bfloat16* __restrict__ W2t,
    const float* __restrict__ b2, const float* __restrict__ r,
    float* __restrict__ out) {
  const int M0 = (blockIdx.x >> 2) * 128;    // token strip
  const int N0 = (blockIdx.x & 3) * 256;     // d quarter

  __shared__ __hip_bfloat16 lds[2][TILE_ELEMS];

  const int tid  = threadIdx.x;
  const int lane = tid & 63;
  const int wid  = tid >> 6;
  const int dg = (wid >> 1) * 64;            // wave d offset in tile
  const int tg = (wid & 1) * 64;             // wave tok offset in tile
  const int laneq = lane >> 4;
  const int lanem = lane & 15;
  const int srow = tid >> 2;
  const int cc8  = (tid & 3) * 8;

  const __hip_bfloat16* gA = Hs + (size_t)(M0 + srow) * EFK + cc8;
  const __hip_bfloat16* gB = W2t + (size_t)(N0 + srow) * EFK + cc8;
  const __hip_bfloat16* gB2 = gB + (size_t)128 * EFK;

  floatx4 acc[4][4];   // [i = d group][j = tok group]
#pragma unroll
  for (int i = 0; i < 4; ++i)
#pragma unroll
    for (int j = 0; j < 4; ++j) acc[i][j] = (floatx4){0.f, 0.f, 0.f, 0.f};

#define STAGEO(p, k0)                                               \
  do {                                                              \
    gld_lds16(gA  + (k0), &lds[p][(size_t)tid * 8]);                \
    gld_lds16(gB  + (k0), &lds[p][(size_t)(512 + tid) * 8]);        \
    gld_lds16(gB2 + (k0), &lds[p][(size_t)(1024 + tid) * 8]);       \
  } while (0)

  STAGEO(0, 0);
  const int KT = EFK / 32;
  for (int kt = 0; kt < KT; ++kt) {
    const int p = kt & 1;
    __syncthreads();
    if (kt + 1 < KT) STAGEO(p ^ 1, (kt + 1) * 32);
    short8 wfr[4], hfr[4];
#pragma unroll
    for (int i = 0; i < 4; ++i)
      wfr[i] = *(const short8*)(&lds[p][TILE_A_ELEMS + (dg + i * 16 + lanem) * 32 + laneq * 8]);
#pragma unroll
    for (int j = 0; j < 4; ++j)
      hfr[j] = *(const short8*)(&lds[p][(tg + j * 16 + lanem) * 32 + laneq * 8]);
#pragma unroll
    for (int i = 0; i < 4; ++i)
#pragma unroll
      for (int j = 0; j < 4; ++j)
        acc[i][j] = __builtin_amdgcn_mfma_f32_16x16x32_bf16(wfr[i], hfr[j], acc[i][j], 0, 0, 0);
  }
#undef STAGEO

  // epilogue: combined bias sum_e r[tok,e]*b2[e,d], float4 store
#pragma unroll
  for (int i = 0; i < 4; ++i) {
    const int d0 = N0 + dg + i * 16 + laneq * 4;         // 4 consecutive d
    float4 b2v[EEXP];
#pragma unroll
    for (int e = 0; e < EEXP; ++e) b2v[e] = *(const float4*)(b2 + e * DDIM + d0);
#pragma unroll
    for (int j = 0; j < 4; ++j) {
      const int tok = M0 + tg + j * 16 + lanem;
      const float4* r4 = (const float4*)(r + (size_t)tok * EEXP);
      const float4 r0 = r4[0], r1 = r4[1];
      const float rv[EEXP] = {r0.x, r0.y, r0.z, r0.w, r1.x, r1.y, r1.z, r1.w};
      float bx = 0.f, by = 0.f, bz = 0.f, bw = 0.f;
#pragma unroll
      for (int e = 0; e < EEXP; ++e) {
        bx += rv[e] * b2v[e].x; by += rv[e] * b2v[e].y;
        bz += rv[e] * b2v[e].z; bw += rv[e] * b2v[e].w;
      }
      float4 o;
      o.x = acc[i][j][0] + bx; o.y = acc[i][j][1] + by;
      o.z = acc[i][j][2] + bz; o.w = acc[i][j][3] + bw;
      *(float4*)(out + (size_t)tok * DDIM + d0) = o;
    }
  }
}

extern "C" void kernel_launch(void* const* d_in, const int* in_sizes, int n_in,
                              void* d_out, int out_size, void* d_ws, size_t ws_size,
                              hipStream_t stream) {
  const float* x  = (const float*)d_in[0];
  const float* W1 = (const float*)d_in[1];
  const float* b1 = (const float*)d_in[2];
  const float* W2 = (const float*)d_in[3];
  const float* b2 = (const float*)d_in[4];
  const float* Wr = (const float*)d_in[5];
  const float* br = (const float*)d_in[6];
  float* out = (float*)d_out;

  char* ws = (char*)d_ws;
  __hip_bfloat16* xbf = (__hip_bfloat16*)(ws);                            // 32 MB
  __hip_bfloat16* W1t = (__hip_bfloat16*)(ws + (32u << 20));              // 8 MB  [E][F][D]
  __hip_bfloat16* W2t = (__hip_bfloat16*)(ws + (40u << 20));              // 8 MB  [D][E*F]
  float*          r   = (float*)(ws + (48u << 20));                       // 0.5 MB [MTOK][E]
  __hip_bfloat16* Hs  = (__hip_bfloat16*)(ws + (48u << 20) + (1u << 19)); // 128 MB [MTOK][E*F]

  // W1 [E][D][F] -> W1t [E][F][D]
  transpose_cast_kernel<<<dim3(FDIM / 32, DDIM / 32, EEXP), 256, 0, stream>>>(W1, W1t, DDIM, FDIM);
  // W2 [E*F][D] -> W2t [D][E*F]
  transpose_cast_kernel<<<dim3(DDIM / 32, EFK / 32, 1), 256, 0, stream>>>(W2, W2t, EFK, DDIM);
  // router softmax + x cast
  router_cast_kernel<<<MTOK / 4, 256, 0, stream>>>(x, Wr, br, xbf, r);
  // stage 1 grouped GEMM (+gelu, +router scale): 128-tok x 256-f tiles
  gemm_h_kernel<<<dim3(MTOK / 128, FDIM / 256, EEXP), 512, 0, stream>>>(xbf, W1t, b1, r, Hs);
  // stage 2 GEMM (+combined bias): 128-tok x 256-d tiles, swizzled flat grid
  gemm_out_kernel<<<dim3((MTOK / 128) * (DDIM / 256)), 512, 0, stream>>>(Hs, W2t, b2, r, out);
}